// Round 7
// baseline (9895.098 us; speedup 1.0000x reference)
//
#include <hip/hip_runtime.h>
#include <stdint.h>

// B=256, T=512, H=256, 4 layers. 16 groups x MB=16 batch rows.
// Per (group,layer) "cell": WG-B (recurrence, W_hh resident, pointwise, h in LDS)
// + WG-A (x-projection, W_ih resident, ships fp32 gate partials via L3 w/ slack).
#define T_ 512
#define H_ 256
#define MB 16
#define NBUF 4

typedef __attribute__((ext_vector_type(8))) short  short8;
typedef __attribute__((ext_vector_type(4))) float  floatx4;
typedef unsigned long long ull;

struct Params {
  const float* x;
  const float* Wih[4]; const float* Whh[4]; const float* bih[4]; const float* bhh[4];
  const float* fcW; const float* fcb;
  int*   fB;      // [64 cells]*32 ints: h's published (fB = t  <=>  h(t-1) readable)
  int*   fA;      // [64 cells]*32 ints: gx published (fA = t+1 <=> gx(t) readable)
  short* hring;   // [64 cells][NBUF][4096] bf16, A-fragment image of h
  float* gxring;  // [48 cells][NBUF][16384] fp32 gate partials (bias included)
};

__device__ __forceinline__ short f2bf(float f){
  uint32_t u = __builtin_bit_cast(uint32_t, f);
  u += 0x7fffu + ((u >> 16) & 1u);
  return (short)(u >> 16);
}
__device__ __forceinline__ float bf2f(short s){
  uint32_t u = ((uint32_t)(uint16_t)s) << 16;
  return __builtin_bit_cast(float, u);
}
__device__ __forceinline__ float sigm(float v){ return 1.0f / (1.0f + __expf(-v)); }
__device__ __forceinline__ float tanh_(float v){
  float a = fabsf(v);
  float e = __expf(-2.0f * a);
  float r = (1.0f - e) / (1.0f + e);
  return v < 0.0f ? -r : r;
}

// Proven L3-coherent exchange (rounds 2/5/6): relaxed agent-scope atomics.
__device__ __forceinline__ ull a_ld64(const ull* p){
  return __hip_atomic_load(p, __ATOMIC_RELAXED, __HIP_MEMORY_SCOPE_AGENT);
}
__device__ __forceinline__ void a_st64(ull* p, ull v){
  __hip_atomic_store(p, v, __ATOMIC_RELAXED, __HIP_MEMORY_SCOPE_AGENT);
}
__device__ __forceinline__ int a_ldi(const int* p){
  return __hip_atomic_load(p, __ATOMIC_RELAXED, __HIP_MEMORY_SCOPE_AGENT);
}
__device__ __forceinline__ void a_sti(int* p, int v){
  __hip_atomic_store(p, v, __ATOMIC_RELAXED, __HIP_MEMORY_SCOPE_AGENT);
}

#define MFMA(a,b,c) __builtin_amdgcn_mfma_f32_16x16x32_bf16((a),(b),(c),0,0,0)

// wave-autonomous poll: each lane has ptr+thr; returns when all lanes satisfied
__device__ __forceinline__ void wpoll(const int* p, int thr, bool& dead){
  if (dead) return;
  int guard = 0;
  for (;;){
    int v = a_ldi(p);
    if (__all((int)(v >= thr))) break;
    if (++guard > (1 << 17)) { dead = true; break; }
  }
}

// load 8 fp32 weights -> bf16 fragment
__device__ __forceinline__ short8 ldw8(const float* p){
  short8 v;
  #pragma unroll
  for (int i = 0; i < 8; ++i) v[i] = f2bf(p[i]);
  return v;
}

// ---- WG-B: recurrence owner for cell (g,l) -------------------------------
template<bool L0>
__device__ __forceinline__ void run_B(const Params& p, int g, int l, short* a_frag){
  const int tid = threadIdx.x;
  const int lane = tid & 63;
  const int wave = tid >> 6;          // 0..7, owns h-dims [wave*32, wave*32+32)
  const int n15 = lane & 15, q4 = lane >> 4;
  const int cell = l * 16 + g;

  int* fB_self = p.fB + cell * 32;
  int* fA_self = p.fA + cell * 32;
  int* fA_down = p.fA + (cell + 16) * 32;
  short* hr = p.hring + (size_t)cell * NBUF * 4096;
  const float* gxr = L0 ? (const float*)nullptr
                        : p.gxring + (size_t)(cell - 16) * NBUF * 16384;

  // Weight fragments: nt = gate*2 + half; col dim = wave*32 + half*16 + n15
  const float* Whh = p.Whh[l];
  short8 wf[8][8];
  float bv[8], wv[8];
  #pragma unroll
  for (int nt = 0; nt < 8; ++nt){
    int dim  = wave * 32 + (nt & 1) * 16 + n15;
    int grow = (nt >> 1) * 256 + dim;
    bv[nt] = p.bih[l][grow] + p.bhh[l][grow];
    if (L0) wv[nt] = p.Wih[0][grow];          // W_ih0 is [1024 x 1]
    #pragma unroll
    for (int kb = 0; kb < 8; ++kb)
      wf[kb][nt] = ldw8(Whh + (size_t)grow * H_ + kb * 32 + q4 * 8);
  }

  float cst[8];
  #pragma unroll
  for (int i = 0; i < 8; ++i) cst[i] = 0.f;

  // h(-1) = 0 into buffer 0
  { ull* zp = (ull*)a_frag + tid * 2; zp[0] = 0; zp[1] = 0; }
  __syncthreads();

  // poll map: lanes<32: gx availability (l>0); lanes>=32: h-ring throttle (l<3)
  const int* pp = (lane < 32) ? (L0 ? fB_self : fA_self)
                              : ((l < 3) ? fA_down : fB_self);
  const int dlt = (lane < 32) ? (L0 ? -1000000 : 1)
                              : ((l < 3) ? -3 : -1000000);
  bool dead = false;

  for (int t = 0; t < T_; ++t){
    short* frag_rd = a_frag + (t & 1) * 4096;          // h(t-1)
    short* frag_wr = a_frag + (1 - (t & 1)) * 4096;    // h(t)

    wpoll(pp, t + dlt, dead);

    // issue gx(t) loads (fp32, lane-linear; hidden under MFMA)
    ull gv[16];
    if (!L0){
      const ull* gp = (const ull*)(gxr + (size_t)(t & 3) * 16384) + tid * 16;
      #pragma unroll
      for (int i = 0; i < 16; ++i) gv[i] = a_ld64(gp + i);
    }
    float xv[4];
    if (L0){
      #pragma unroll
      for (int r = 0; r < 4; ++r)
        xv[r] = p.x[(size_t)(g * MB + q4 * 4 + r) * T_ + t];
    }

    // deferred publish: copy h(t-1) frag image -> ring slot (t-1)&3
    if (t > 0){
      const ull* hs = (const ull*)frag_rd + tid * 2;
      ull* hd = (ull*)(hr + (size_t)((t - 1) & 3) * 4096) + tid * 2;
      a_st64(hd, hs[0]);
      a_st64(hd + 1, hs[1]);
    }

    // MFMA: gates_h = W_hh * h(t-1), K=256, per-wave N=128 (8 n-tiles)
    floatx4 acc[8];
    #pragma unroll
    for (int nt = 0; nt < 8; ++nt) acc[nt] = floatx4{0.f,0.f,0.f,0.f};
    #pragma unroll
    for (int kb = 0; kb < 8; ++kb){
      short8 af = *(const short8*)(frag_rd + kb * 512 + lane * 8);
      #pragma unroll
      for (int nt = 0; nt < 8; ++nt)
        acc[nt] = MFMA(af, wf[kb][nt], acc[nt]);
    }
    if (!L0){
      #pragma unroll
      for (int nt = 0; nt < 8; ++nt){
        float2 lo = __builtin_bit_cast(float2, gv[nt*2]);
        float2 hi = __builtin_bit_cast(float2, gv[nt*2+1]);
        acc[nt][0] += lo.x; acc[nt][1] += lo.y;
        acc[nt][2] += hi.x; acc[nt][3] += hi.y;
      }
    } else {
      #pragma unroll
      for (int nt = 0; nt < 8; ++nt)
        #pragma unroll
        for (int r = 0; r < 4; ++r)
          acc[nt][r] += bv[nt] + xv[r] * wv[nt];
    }

    // pointwise fully in-register: lane owns (4 rows x 2 dims)
    #pragma unroll
    for (int half = 0; half < 2; ++half){
      #pragma unroll
      for (int r = 0; r < 4; ++r){
        float gi = acc[0 + half][r];
        float gf = acc[2 + half][r];
        float gg = acc[4 + half][r];
        float go = acc[6 + half][r];
        float iv = sigm(gi), fv = sigm(gf), gt = tanh_(gg), ov = sigm(go);
        float c = fv * cst[half*4 + r] + iv * gt;
        cst[half*4 + r] = c;
        float h = ov * tanh_(c);
        // write h(t) into A-fragment position (kb=wave, koff=half*16+n15, m=q4*4+r)
        frag_wr[wave * 512 + ((half*2 + (n15>>3))*16 + q4*4 + r)*8 + (n15 & 7)] = f2bf(h);
      }
    }

    __builtin_amdgcn_s_waitcnt(0);       // ring stores drained (per-thread)
    __syncthreads();
    if (tid == 0 && t > 0) a_sti(fB_self, t);    // h(t-1) published
  }

  // epilogue: publish h(T-1)
  {
    const ull* hs = (const ull*)(a_frag + (T_ & 1) * 4096) + tid * 2;
    ull* hd = (ull*)(hr + (size_t)((T_ - 1) & 3) * 4096) + tid * 2;
    a_st64(hd, hs[0]);
    a_st64(hd + 1, hs[1]);
    __builtin_amdgcn_s_waitcnt(0);
    __syncthreads();
    if (tid == 0) a_sti(fB_self, T_);
  }
}

// ---- WG-A: x-projection for cell (g,l), l>=1 -----------------------------
__device__ __forceinline__ void run_A(const Params& p, int g, int l, short* a_frag){
  const int tid = threadIdx.x;
  const int lane = tid & 63;
  const int wave = tid >> 6;
  const int n15 = lane & 15, q4 = lane >> 4;
  const int cell = l * 16 + g, up = cell - 16;
  int* fA_self = p.fA + cell * 32;
  int* fB_self = p.fB + cell * 32;
  int* fB_up   = p.fB + up * 32;
  const short* hr_up = p.hring + (size_t)up * NBUF * 4096;
  float* gxr = p.gxring + (size_t)(cell - 16) * NBUF * 16384;

  const float* Wih = p.Wih[l];
  short8 wf[8][8];
  float bv[8];
  #pragma unroll
  for (int nt = 0; nt < 8; ++nt){
    int dim  = wave * 32 + (nt & 1) * 16 + n15;
    int grow = (nt >> 1) * 256 + dim;
    bv[nt] = p.bih[l][grow] + p.bhh[l][grow];
    #pragma unroll
    for (int kb = 0; kb < 8; ++kb)
      wf[kb][nt] = ldw8(Wih + (size_t)grow * H_ + kb * 32 + q4 * 8);
  }

  bool dead = false;
  // prologue: stage x(0) = h_up(0)
  {
    wpoll(fB_up, 1, dead);
    const ull* sp = (const ull*)hr_up + tid * 2;
    ull v0 = a_ld64(sp), v1 = a_ld64(sp + 1);
    ull* dp = (ull*)a_frag + tid * 2;
    dp[0] = v0; dp[1] = v1;
  }
  __syncthreads();

  const int* pp = (lane < 32) ? fB_self : fB_up;
  for (int t = 0; t < T_; ++t){
    short* frag_rd = a_frag + (t & 1) * 4096;
    short* frag_wr = a_frag + (1 - (t & 1)) * 4096;
    const bool pf = (t + 1 < T_);
    // lanes<32: gx-ring throttle; lanes>=32: upstream h(t+1) for prefetch
    int thr = (lane < 32) ? (t - 3) : (pf ? (t + 2) : -1000000);
    wpoll(pp, thr, dead);

    // prefetch x(t+1)
    ull pv0 = 0, pv1 = 0;
    if (pf){
      const ull* sp = (const ull*)(hr_up + (size_t)((t + 1) & 3) * 4096) + tid * 2;
      pv0 = a_ld64(sp); pv1 = a_ld64(sp + 1);
    }

    // gates_x = W_ih * x(t) + bias
    floatx4 acc[8];
    #pragma unroll
    for (int nt = 0; nt < 8; ++nt) acc[nt] = floatx4{bv[nt],bv[nt],bv[nt],bv[nt]};
    #pragma unroll
    for (int kb = 0; kb < 8; ++kb){
      short8 af = *(const short8*)(frag_rd + kb * 512 + lane * 8);
      #pragma unroll
      for (int nt = 0; nt < 8; ++nt)
        acc[nt] = MFMA(af, wf[kb][nt], acc[nt]);
    }
    // ship fp32 partials, lane-linear (consumer uses identical tid->acc map)
    {
      ull* gp = (ull*)(gxr + (size_t)(t & 3) * 16384) + tid * 16;
      #pragma unroll
      for (int nt = 0; nt < 8; ++nt){
        float2 lo{acc[nt][0], acc[nt][1]};
        float2 hi{acc[nt][2], acc[nt][3]};
        a_st64(gp + nt*2,     __builtin_bit_cast(ull, lo));
        a_st64(gp + nt*2 + 1, __builtin_bit_cast(ull, hi));
      }
    }
    __builtin_amdgcn_s_waitcnt(0);       // gx stores + prefetch loads done
    if (pf){
      ull* dp = (ull*)frag_wr + tid * 2;
      dp[0] = pv0; dp[1] = pv1;
    }
    __syncthreads();
    if (tid == 0) a_sti(fA_self, t + 1);   // gx(t) published
  }
}

__global__ __launch_bounds__(512, 2) void lstm_kernel(Params p){
  __shared__ short a_frag[2 * 4096];     // 16 KB double-buffered A-fragments
  const int bid = blockIdx.x;
  if (bid < 64){
    int l = bid >> 4, g = bid & 15;
    if (l == 0) run_B<true >(p, g, 0, a_frag);
    else        run_B<false>(p, g, l, a_frag);
  } else {
    int idx = bid - 64;
    int l = (idx >> 4) + 1, g = idx & 15;
    run_A(p, g, l, a_frag);
  }
}

// FC on h_3(T-1): decode A-fragment image at ring slot (T-1)&3
__global__ void fc_kernel(const short* __restrict__ hring, const float* __restrict__ fcW,
                          const float* __restrict__ fcb, float* __restrict__ out){
  int b = blockIdx.x, lane = threadIdx.x;
  int g = b >> 4, m = b & 15;
  const short* base = hring + (size_t)(3 * 16 + g) * NBUF * 4096
                    + (size_t)((T_ - 1) & 3) * 4096;
  float s = 0.f;
  #pragma unroll
  for (int k = 0; k < 4; ++k){
    int dim = lane + 64 * k;
    int kb = dim >> 5, koff = dim & 31;
    short hv = base[kb * 512 + ((koff >> 3) * 16 + m) * 8 + (koff & 7)];
    s += bf2f(hv) * fcW[dim];
  }
  #pragma unroll
  for (int off = 32; off; off >>= 1) s += __shfl_down(s, off);
  if (lane == 0) out[b] = s + fcb[0];
}

extern "C" void kernel_launch(void* const* d_in, const int* in_sizes, int n_in,
                              void* d_out, int out_size, void* d_ws, size_t ws_size,
                              hipStream_t stream) {
  Params P;
  P.x = (const float*)d_in[0];
  for (int l = 0; l < 4; ++l){
    P.Wih[l] = (const float*)d_in[1 + 4*l];
    P.Whh[l] = (const float*)d_in[2 + 4*l];
    P.bih[l] = (const float*)d_in[3 + 4*l];
    P.bhh[l] = (const float*)d_in[4 + 4*l];
  }
  P.fcW = (const float*)d_in[17];
  P.fcb = (const float*)d_in[18];

  char* ws = (char*)d_ws;
  P.fB     = (int*)ws;                          // 8 KB
  P.fA     = (int*)(ws + 8192);                 // 8 KB
  P.hring  = (short*)(ws + 65536);              // 64*4*8KB = 2 MB
  P.gxring = (float*)(ws + 65536 + (2u << 20)); // 48*4*64KB = 12 MB

  hipMemsetAsync(ws, 0, 16384, stream);
  hipLaunchKernelGGL(lstm_kernel, dim3(112), dim3(512), 0, stream, P);
  hipLaunchKernelGGL(fc_kernel, dim3(256), dim3(64), 0, stream,
                     P.hring, P.fcW, P.fcb, (float*)d_out);
}